// Round 3
// baseline (334.321 us; speedup 1.0000x reference)
//
#include <hip/hip_runtime.h>
#include <hip/hip_cooperative_groups.h>
#include <math.h>

namespace cg = cooperative_groups;

// L = 2*pi * log2(e): exp(-2pi r^2) == exp2(-L r^2)
#define LCONST 9.064720283654388f

// 5x5x5 cells of size 2.0 over [0,10)^3. Cutoff r=2: dropped terms are
// exp2(-L*4) ~ 1.2e-11 each vs theta ~0.36 -> below f32 ulp: exact.
#define NC 5
#define NCELL 125
#define DOMCAP 192   // dom pts/cell: mean 131, sigma ~11.4 -> +5.3 sigma
#define C1CAP 32     // C1 pts/cell/batch: mean 8.2 -> astronomically safe
#define CCAP 32
#define LISTCAP 320  // packed 27-bin neighborhood: mean 221, sigma ~15 -> +6.6 sigma
#define GRID 500
#define TPB 192

__device__ __forceinline__ float fexp2(float x) {
#if defined(__has_builtin)
#if __has_builtin(__builtin_amdgcn_exp2f)
    return __builtin_amdgcn_exp2f(x);
#else
    return exp2f(x);
#endif
#else
    return exp2f(x);
#endif
}

__device__ __forceinline__ int cell_of(float x, float y, float z) {
    int cx = (int)(x * 0.5f); cx = cx < 0 ? 0 : (cx > NC - 1 ? NC - 1 : cx);
    int cy = (int)(y * 0.5f); cy = cy < 0 ? 0 : (cy > NC - 1 ? NC - 1 : cy);
    int cz = (int)(z * 0.5f); cz = cz < 0 ? 0 : (cz > NC - 1 ? NC - 1 : cz);
    return (cx * NC + cy) * NC + cz;
}

// Pack the 27-neighborhood bins of (cx,cy,cz) into one contiguous LDS list.
// Turns 27 short dynamic loops with dependent global loads (110 cyc/pair,
// latency-bound -- round-2 counters) into ONE contiguous LDS scan.
__device__ __forceinline__ int stage_list(int cx, int cy, int cz,
                                          const float4* __restrict__ Pbin,
                                          const int* __restrict__ cnt, int cap,
                                          float4* slist, int* sbcnt, int* sboff,
                                          int* snlist, int tid) {
    __syncthreads();   // protect LDS against previous task's readers
    if (tid < 27) {
        int dx = tid / 9 - 1, dy = (tid / 3) % 3 - 1, dz = tid % 3 - 1;
        int x2 = cx + dx, y2 = cy + dy, z2 = cz + dz;
        bool ok = ((unsigned)x2 < (unsigned)NC) && ((unsigned)y2 < (unsigned)NC) &&
                  ((unsigned)z2 < (unsigned)NC);
        int cc = (x2 * NC + y2) * NC + z2;
        sbcnt[tid] = ok ? min(cnt[cc], cap) : 0;   // clamp: overflow can't OOB
    }
    __syncthreads();
    if (tid == 0) {
        int off = 0;
        #pragma unroll
        for (int j = 0; j < 27; ++j) { sboff[j] = off; off += sbcnt[j]; }
        *snlist = min(off, LISTCAP);
    }
    __syncthreads();
    #pragma unroll 1
    for (int j = 0; j < 27; ++j) {
        int nj = sbcnt[j];                 // nj <= 32 <= wave width
        if (tid < nj) {
            int dst = sboff[j] + tid;
            if (dst < LISTCAP) {
                int dx = j / 9 - 1, dy = (j / 3) % 3 - 1, dz = j % 3 - 1;
                int cc = ((cx + dx) * NC + (cy + dy)) * NC + (cz + dz);
                slist[dst] = Pbin[cc * cap + tid];
            }
        }
    }
    __syncthreads();
    return *snlist;
}

// Contiguous scan: arg = 2L d.q - L|q|^2 - L|d|^2 = -L||d-q||^2 <= 0, kept in
// ONE exp2 argument (factoring exp2(d.w) out overflows: inf*0=NaN, round-1 bug).
__device__ __forceinline__ float scan_list(float4 d, const float4* __restrict__ slist,
                                           int n) {
    float acc = 0.0f;
    #pragma unroll 4
    for (int i = 0; i < n; ++i) {
        float4 q = slist[i];
        float arg = fmaf(d.x, q.x, fmaf(d.y, q.y, fmaf(d.z, q.z, d.w + q.w)));
        acc += fexp2(arg);
    }
    return acc;
}

// counters layout (ints): [cntD 125][cntC1 2000][cntC 125][prod 16] = 2266 words
__global__ void __launch_bounds__(TPB) k_fused(
    const float* __restrict__ C1, const float* __restrict__ C,
    const float* __restrict__ dom, float* __restrict__ out,
    float4* __restrict__ PDbin, float4* __restrict__ P1bin,
    float4* __restrict__ PCbin, float* __restrict__ TC,
    int* __restrict__ cnts) {
    cg::grid_group grid = cg::this_grid();
    const int tid = threadIdx.x;
    int* cntD  = cnts;
    int* cntC1 = cnts + NCELL;
    int* cntC  = cnts + NCELL + 16 * NCELL;
    float* prod = (float*)(cnts + 2250);

    __shared__ float4 slist[LISTCAP];
    __shared__ int sbcnt[27];
    __shared__ int sboff[27];
    __shared__ int snlist;
    __shared__ float spartial[3];

    // ---- phase 0: zero counters + prod (workspace is re-poisoned per run) ----
    for (int t = blockIdx.x * TPB + tid; t < 2266; t += GRID * TPB) cnts[t] = 0;
    grid.sync();

    // ---- phase 1: bin all three point sets (atomic append; sums order-free) ----
    {
        int t = blockIdx.x * TPB + tid;   // GRID*TPB = 96000 covers 33792
        if (t < 16384) {
            float x = dom[3 * t], y = dom[3 * t + 1], z = dom[3 * t + 2];
            int cell = cell_of(x, y, z);
            int s = atomicAdd(cntD + cell, 1);
            if (s < DOMCAP)
                PDbin[cell * DOMCAP + s] =
                    make_float4(2.0f * LCONST * x, 2.0f * LCONST * y, 2.0f * LCONST * z,
                                -LCONST * (x * x + y * y + z * z));
        } else if (t < 32768) {
            int j = t - 16384;
            float x = C1[3 * j], y = C1[3 * j + 1], z = C1[3 * j + 2];
            int b = j >> 10;
            int cell = cell_of(x, y, z);
            int s = atomicAdd(cntC1 + b * NCELL + cell, 1);
            if (s < C1CAP)
                P1bin[(b * NCELL + cell) * C1CAP + s] =
                    make_float4(x, y, z, -LCONST * (x * x + y * y + z * z));
        } else if (t < 33792) {
            int j = t - 32768;
            float x = C[3 * j], y = C[3 * j + 1], z = C[3 * j + 2];
            int cell = cell_of(x, y, z);
            int s = atomicAdd(cntC + cell, 1);
            if (s < CCAP)
                PCbin[cell * CCAP + s] =
                    make_float4(x, y, z, -LCONST * (x * x + y * y + z * z));
        }
    }
    grid.sync();

    // ---- phase 2: theta_C per dom slot (block = cell; 192 threads = 192 slots) ----
    for (int cell = blockIdx.x; cell < NCELL; cell += GRID) {
        int cx = cell / 25, cy = (cell / 5) % 5, cz = cell % 5;
        int n = stage_list(cx, cy, cz, PCbin, cntC, CCAP, slist, sbcnt, sboff,
                           &snlist, tid);
        int len = min(cntD[cell], DOMCAP);
        int slot = cell * DOMCAP + tid;
        float4 d = make_float4(0.f, 0.f, 0.f, 0.f);   // sanitize poison
        if (tid < len) d = PDbin[slot];
        float acc = 0.0f;
        if ((tid & ~63) < len)            // wave-uniform: skip fully-dead waves
            acc = scan_list(d, slist, n);
        TC[slot] = acc;                   // finite for ALL 192 slots of this cell
    }
    grid.sync();

    // ---- phase 3: main (block task = (b,cell); theta_b * theta_C, reduce) ----
    for (int task = blockIdx.x; task < 16 * NCELL; task += GRID) {
        int cell = task % NCELL, b = task / NCELL;
        int cx = cell / 25, cy = (cell / 5) % 5, cz = cell % 5;
        int n = stage_list(cx, cy, cz, P1bin + b * (NCELL * C1CAP),
                           cntC1 + b * NCELL, C1CAP, slist, sbcnt, sboff,
                           &snlist, tid);
        int len = min(cntD[cell], DOMCAP);
        int slot = cell * DOMCAP + tid;
        float4 d = make_float4(0.f, 0.f, 0.f, 0.f);
        if (tid < len) d = PDbin[slot];
        float acc = 0.0f;
        if ((tid & ~63) < len)
            acc = scan_list(d, slist, n);
        float v = acc * TC[slot];
        v = (tid < len) ? v : 0.0f;       // select, not multiply: NaN-safe
        for (int off = 32; off; off >>= 1) v += __shfl_down(v, off, 64);
        int lane = tid & 63, wid = tid >> 6;
        if (lane == 0) spartial[wid] = v;
        __syncthreads();
        if (tid == 0)
            atomicAdd(prod + b, spartial[0] + spartial[1] + spartial[2]);
        // stage_list's leading __syncthreads protects LDS reuse next iteration
    }
    grid.sync();

    // ---- phase 4: finalize ----
    if (blockIdx.x == 0 && tid < 16) {
        const float scale = 4.76837158203125e-4f;  // A*V/1024 = 8*(1000/16384)/1024
        float dot = prod[tid] * scale;
        dot = fminf(fmaxf(dot, 0.0f), 1.0f);
        out[tid] = 1.0f - dot;
    }
}

extern "C" void kernel_launch(void* const* d_in, const int* in_sizes, int n_in,
                              void* d_out, int out_size, void* d_ws, size_t ws_size,
                              hipStream_t stream) {
    const float* C1  = (const float*)d_in[0];   // (16,1024,3)
    const float* C   = (const float*)d_in[1];   // (1024,3)
    const float* dom = (const float*)d_in[2];   // (16384,3)
    float* out = (float*)d_out;                 // (16,)

    char* ws = (char*)d_ws;
    float4* PDbin = (float4*)(ws + 0);          // 125*192*16   =   384000
    float4* P1bin = (float4*)(ws + 384000);     // 16*125*32*16 =  1024000
    float4* PCbin = (float4*)(ws + 1408000);    // 125*32*16    =    64000
    float*  TC    = (float*)(ws + 1472000);     // 125*192*4    =    96000
    int*    cnts  = (int*)(ws + 1568000);       // 2266 words   ->   ~1.58MB total

    void* args[] = {(void*)&C1, (void*)&C, (void*)&dom, (void*)&out,
                    (void*)&PDbin, (void*)&P1bin, (void*)&PCbin, (void*)&TC,
                    (void*)&cnts};
    hipLaunchCooperativeKernel((const void*)k_fused, dim3(GRID), dim3(TPB),
                               args, 0, stream);
}

// Round 4
// 223.996 us; speedup vs baseline: 1.4925x; 1.4925x over previous
//
#include <hip/hip_runtime.h>
#include <math.h>

// L = 2*pi * log2(e): exp(-2pi r^2) == exp2(-L r^2)
#define LCONST 9.064720283654388f

// 5x5x5 cells of size 2.0 over [0,10)^3. Cutoff r=2: dropped terms are
// exp2(-L*4) ~ 1.2e-11 each vs theta ~0.36 -> below one f32 ulp: exact.
#define NC 5
#define NCELL 125
#define DOMCAP 192    // dom pts/cell: mean 131, sigma 11.4 -> +5.3 sigma
#define LISTCAP 320   // packed 27-neighborhood list: mean <=221, sigma 13.2 -> +7.5 sigma
#define NB 16
#define MAIN_BLOCKS 1500
#define NTASK (MAIN_BLOCKS * 4)   // 6000 wave-tasks = 16 b x 125 cells x 3 chunks

__device__ __forceinline__ float fexp2(float x) {
#if defined(__has_builtin)
#if __has_builtin(__builtin_amdgcn_exp2f)
    return __builtin_amdgcn_exp2f(x);
#else
    return exp2f(x);
#endif
#else
    return exp2f(x);
#endif
}

__device__ __forceinline__ int3 cell3_of(float x, float y, float z) {
    int cx = (int)(x * 0.5f); cx = cx < 0 ? 0 : (cx > NC - 1 ? NC - 1 : cx);
    int cy = (int)(y * 0.5f); cy = cy < 0 ? 0 : (cy > NC - 1 ? NC - 1 : cy);
    int cz = (int)(z * 0.5f); cz = cz < 0 ? 0 : (cz > NC - 1 ? NC - 1 : cz);
    return make_int3(cx, cy, cz);
}

// cnts word layout: [cntD 125][cntL1 2000][cntLC 125][prod 16 floats][done 1] = 2267
#define W_CNTD 0
#define W_CNTL1 NCELL
#define W_CNTLC (NCELL + NB * NCELL)
#define W_PROD 2250
#define W_DONE 2266
#define W_TOTAL 2267

// One kernel bins dom into per-cell slots AND scatters C1/C points into the
// packed neighborhood list of every cell within their 27-neighborhood.
// This builds round-2's "bin loops" as ONE contiguous list per (b,cell) in
// global memory, once -- k_main then scans contiguously (round-3's LDS
// staging paid this cost per task and serially; here it's parallel and once).
// Slot order within a list is nondeterministic but sums are order-free.
__global__ void __launch_bounds__(256) k_bin(const float* __restrict__ C1,
                                             const float* __restrict__ C,
                                             const float* __restrict__ dom,
                                             float4* __restrict__ PDbin,
                                             float4* __restrict__ L1,
                                             float4* __restrict__ LC,
                                             int* __restrict__ cnts) {
    int* cntD  = cnts + W_CNTD;
    int* cntL1 = cnts + W_CNTL1;
    int* cntLC = cnts + W_CNTLC;
    int t = blockIdx.x * 256 + threadIdx.x;   // 1900*256 = 486400 threads exactly
    if (t < 16384) {
        float x = dom[3 * t], y = dom[3 * t + 1], z = dom[3 * t + 2];
        int3 c = cell3_of(x, y, z);
        int cell = (c.x * NC + c.y) * NC + c.z;
        int s = atomicAdd(cntD + cell, 1);
        if (s < DOMCAP)   // clamp: overflowed bins can't OOB
            PDbin[cell * DOMCAP + s] =
                make_float4(2.0f * LCONST * x, 2.0f * LCONST * y, 2.0f * LCONST * z,
                            -LCONST * (x * x + y * y + z * z));
    } else if (t < 16384 + 16384 * 27) {
        int u = t - 16384;
        int j = u / 27, nb = u % 27;          // point j, neighbor-offset nb
        float x = C1[3 * j], y = C1[3 * j + 1], z = C1[3 * j + 2];
        int b = j >> 10;
        int3 c = cell3_of(x, y, z);
        int x2 = c.x + nb / 9 - 1, y2 = c.y + (nb / 3) % 3 - 1, z2 = c.z + nb % 3 - 1;
        if ((unsigned)x2 < (unsigned)NC && (unsigned)y2 < (unsigned)NC &&
            (unsigned)z2 < (unsigned)NC) {
            int cc = (x2 * NC + y2) * NC + z2;
            int s = atomicAdd(cntL1 + b * NCELL + cc, 1);
            if (s < LISTCAP)
                L1[(b * NCELL + cc) * LISTCAP + s] =
                    make_float4(x, y, z, -LCONST * (x * x + y * y + z * z));
        }
    } else if (t < 16384 + 16384 * 27 + 1024 * 27) {
        int u = t - 16384 - 16384 * 27;
        int j = u / 27, nb = u % 27;
        float x = C[3 * j], y = C[3 * j + 1], z = C[3 * j + 2];
        int3 c = cell3_of(x, y, z);
        int x2 = c.x + nb / 9 - 1, y2 = c.y + (nb / 3) % 3 - 1, z2 = c.z + nb % 3 - 1;
        if ((unsigned)x2 < (unsigned)NC && (unsigned)y2 < (unsigned)NC &&
            (unsigned)z2 < (unsigned)NC) {
            int cc = (x2 * NC + y2) * NC + z2;
            int s = atomicAdd(cntLC + cc, 1);
            if (s < LISTCAP)
                LC[cc * LISTCAP + s] =
                    make_float4(x, y, z, -LCONST * (x * x + y * y + z * z));
        }
    }
}

// Wave-task = (b, cell, chunk-of-64-dom-points). Two contiguous scans per wave
// (theta_b over L1[b,cell], theta_C over LC[cell] -- theta_C recomputed per
// batch: +8us busy, but deletes the k_tc dispatch, -18us gap). List pointers
// and trip counts forced wave-uniform via readfirstlane -> s_load_dwordx4:
// scalar-pipe loads leave VALU free, contiguous loop pipelines under unroll.
// CRITICAL: full exponent arg = -L||d-q||^2 <= 0 stays in ONE exp2 argument
// (factoring exp2(d.w) out overflows: inf*0=NaN -- round-1 bug).
__global__ void __launch_bounds__(256) k_main(const float4* __restrict__ PDbin,
                                              const float4* __restrict__ L1,
                                              const float4* __restrict__ LC,
                                              int* __restrict__ cnts,
                                              float* __restrict__ out) {
    const int* cntD  = cnts + W_CNTD;
    const int* cntL1 = cnts + W_CNTL1;
    const int* cntLC = cnts + W_CNTLC;
    float* prod = (float*)(cnts + W_PROD);
    unsigned* done = (unsigned*)(cnts + W_DONE);

    int lane = threadIdx.x & 63;
    int wtask = __builtin_amdgcn_readfirstlane(blockIdx.x * 4 + (threadIdx.x >> 6));
    int chunk = wtask % 3;
    int rest  = wtask / 3;
    int cell  = rest % NCELL;
    int b     = rest / NCELL;

    int len = __builtin_amdgcn_readfirstlane(min(cntD[cell], DOMCAP)) - chunk * 64;
    if (len > 0) {                            // wave-uniform branch
        float4 d = make_float4(0.f, 0.f, 0.f, 0.f);   // sanitize poison lanes
        if (lane < len) d = PDbin[cell * DOMCAP + chunk * 64 + lane];
        int n1 = __builtin_amdgcn_readfirstlane(min(cntL1[b * NCELL + cell], LISTCAP));
        int nc = __builtin_amdgcn_readfirstlane(min(cntLC[cell], LISTCAP));
        const float4* __restrict__ Lb = L1 + (size_t)(b * NCELL + cell) * LISTCAP;
        const float4* __restrict__ Lc = LC + (size_t)cell * LISTCAP;
        float accb = 0.0f, accc = 0.0f;
        #pragma unroll 4
        for (int i = 0; i < n1; ++i) {
            float4 q = Lb[i];
            float arg = fmaf(d.x, q.x, fmaf(d.y, q.y, fmaf(d.z, q.z, d.w + q.w)));
            accb += fexp2(arg);
        }
        #pragma unroll 4
        for (int i = 0; i < nc; ++i) {
            float4 q = Lc[i];
            float arg = fmaf(d.x, q.x, fmaf(d.y, q.y, fmaf(d.z, q.z, d.w + q.w)));
            accc += fexp2(arg);
        }
        float v = (lane < len) ? accb * accc : 0.0f;   // select, not multiply: NaN-safe
        for (int off = 32; off; off >>= 1) v += __shfl_down(v, off, 64);
        if (lane == 0) atomicAdd(prod + b, v);
    }

    // Finalize folded in: every wave (live or empty) takes a ticket; the
    // 6000th wave reads prod coherently (atomic read) and writes out.
    __threadfence();
    unsigned old = 0;
    if (lane == 0) old = atomicAdd(done, 1u);
    old = __shfl(old, 0, 64);
    if (old == NTASK - 1) {
        __threadfence();
        if (lane < 16) {
            const float scale = 4.76837158203125e-4f;  // A*V/1024
            float p = atomicAdd(prod + lane, 0.0f);    // coherent L2 read
            float dot = fminf(fmaxf(p * scale, 0.0f), 1.0f);
            out[lane] = 1.0f - dot;
        }
    }
}

extern "C" void kernel_launch(void* const* d_in, const int* in_sizes, int n_in,
                              void* d_out, int out_size, void* d_ws, size_t ws_size,
                              hipStream_t stream) {
    const float* C1  = (const float*)d_in[0];   // (16,1024,3)
    const float* C   = (const float*)d_in[1];   // (1024,3)
    const float* dom = (const float*)d_in[2];   // (16384,3)
    float* out = (float*)d_out;                 // (16,)

    char* ws = (char*)d_ws;
    float4* PDbin = (float4*)(ws + 0);           // 125*192*16      =   384000
    float4* L1    = (float4*)(ws + 384000);      // 2000*320*16     = 10240000 -> 10624000
    float4* LC    = (float4*)(ws + 10624000);    // 125*320*16      =   640000 -> 11264000
    int*    cnts  = (int*)(ws + 11264000);       // 2267 words      -> ~11.27 MB total

    hipMemsetAsync(cnts, 0, W_TOTAL * 4, stream);
    k_bin<<<1900, 256, 0, stream>>>(C1, C, dom, PDbin, L1, LC, cnts);
    k_main<<<MAIN_BLOCKS, 256, 0, stream>>>(PDbin, L1, LC, cnts, out);
}

// Round 5
// 222.194 us; speedup vs baseline: 1.5046x; 1.0081x over previous
//
#include <hip/hip_runtime.h>
#include <math.h>

// L = 2*pi * log2(e): exp(-2pi r^2) == exp2(-L r^2)
#define LCONST 9.064720283654388f

// dom binned into 5x5x5 cells (size 2.0) over [0,10)^3; C1/C binned by (x,y)
// COLUMN only (25 columns). A cell's scan = <=9 CONTIGUOUS column runs; the
// missing z-filter is free because out-of-cutoff pairs underflow exp2 to 0.
// Cutoff r=2: dropped terms ~1.2e-11 vs theta ~0.36 -> below f32 ulp: exact.
#define NC 5
#define NCELL 125
#define NCOL 25
#define DOMCAP 192   // dom/cell: mean 131, sigma 11.4 -> +5.3 sigma (r2/r4 passed)
#define COLCAP 96    // C1 pts/(b,col): mean 41, sigma 6.4 -> +8.6 sigma
#define NB 16
#define GRID1 132            // 132*256 = 33792 = exactly all points to bin
#define MAIN_BLOCKS 1500
#define NTASK (MAIN_BLOCKS * 4)   // 6000 = 16 b x 125 cells x 3 chunks
#define NTASKC (NCELL * 3)        // 375 theta_C wave-tasks

// cnts word layout
#define W_CNTD 0      // 125
#define W_CNTC1 125   // 16*25 = 400
#define W_CNTC 525    // 25
#define W_PROD 550    // 16 floats
#define W_DONE 566    // ticket
#define W_BAR 567     // spin barrier
#define W_TOTAL 568

__device__ __forceinline__ float fexp2(float x) {
#if defined(__has_builtin)
#if __has_builtin(__builtin_amdgcn_exp2f)
    return __builtin_amdgcn_exp2f(x);
#else
    return exp2f(x);
#endif
#else
    return exp2f(x);
#endif
}

__device__ __forceinline__ int clamp5(float v) {
    int c = (int)(v * 0.5f);
    return c < 0 ? 0 : (c > NC - 1 ? NC - 1 : c);
}

// <=9 contiguous column scans. All control flow wave-uniform; loads are
// wave-uniform broadcasts from L1/L2-resident arrays (614KB total C1).
// CRITICAL: full exponent arg = -L||d-q||^2 <= 0 stays in ONE exp2 argument
// (factoring exp2(d.w) out overflows: inf*0=NaN -- round-1 bug).
// Two accumulators break the serial add dependency chain.
__device__ __forceinline__ float scan_cols(float4 d, int cx, int cy,
                                           const float4* __restrict__ cols,
                                           const int* __restrict__ cnt) {
    float acc0 = 0.0f, acc1 = 0.0f;
    #pragma unroll
    for (int dx = -1; dx <= 1; ++dx) {
        int x2 = cx + dx;
        if ((unsigned)x2 >= (unsigned)NC) continue;
        #pragma unroll
        for (int dy = -1; dy <= 1; ++dy) {
            int y2 = cy + dy;
            if ((unsigned)y2 >= (unsigned)NC) continue;
            int col = x2 * NC + y2;
            int n = __builtin_amdgcn_readfirstlane(min(cnt[col], COLCAP));
            const float4* __restrict__ p = cols + col * COLCAP;
            int i = 0;
            #pragma unroll 2
            for (; i + 2 <= n; i += 2) {
                float4 qa = p[i], qb = p[i + 1];
                float a0 = fmaf(d.x, qa.x, fmaf(d.y, qa.y, fmaf(d.z, qa.z, d.w + qa.w)));
                float a1 = fmaf(d.x, qb.x, fmaf(d.y, qb.y, fmaf(d.z, qb.z, d.w + qb.w)));
                acc0 += fexp2(a0);
                acc1 += fexp2(a1);
            }
            if (i < n) {
                float4 qa = p[i];
                acc0 += fexp2(fmaf(d.x, qa.x, fmaf(d.y, qa.y, fmaf(d.z, qa.z, d.w + qa.w))));
            }
        }
    }
    return acc0 + acc1;
}

// Bin everything, spin-barrier (132 co-resident blocks; same release/acquire
// fence + device-atomic mechanism as cg grid.sync and the round-4 ticket),
// then compute TC = theta_C per dom slot. Slot order in bins is
// nondeterministic but sums are order-free.
__global__ void __launch_bounds__(256) k_bin(const float* __restrict__ C1,
                                             const float* __restrict__ C,
                                             const float* __restrict__ dom,
                                             float4* __restrict__ PDbin,
                                             float4* __restrict__ C1col,
                                             float4* __restrict__ Ccol,
                                             float* __restrict__ TC,
                                             int* __restrict__ cnts) {
    int* cntD  = cnts + W_CNTD;
    int* cntC1 = cnts + W_CNTC1;
    int* cntC  = cnts + W_CNTC;
    unsigned* bar = (unsigned*)(cnts + W_BAR);
    int t = blockIdx.x * 256 + threadIdx.x;   // 0..33791 exactly
    if (t < 16384) {
        float x = dom[3 * t], y = dom[3 * t + 1], z = dom[3 * t + 2];
        int cell = (clamp5(x) * NC + clamp5(y)) * NC + clamp5(z);
        int s = atomicAdd(cntD + cell, 1);
        if (s < DOMCAP)   // clamp: overflowed bins can't OOB
            PDbin[cell * DOMCAP + s] =
                make_float4(2.0f * LCONST * x, 2.0f * LCONST * y, 2.0f * LCONST * z,
                            -LCONST * (x * x + y * y + z * z));
    } else if (t < 32768) {
        int j = t - 16384;
        float x = C1[3 * j], y = C1[3 * j + 1], z = C1[3 * j + 2];
        int b = j >> 10;
        int col = clamp5(x) * NC + clamp5(y);
        int s = atomicAdd(cntC1 + b * NCOL + col, 1);
        if (s < COLCAP)
            C1col[(b * NCOL + col) * COLCAP + s] =
                make_float4(x, y, z, -LCONST * (x * x + y * y + z * z));
    } else {
        int j = t - 32768;
        float x = C[3 * j], y = C[3 * j + 1], z = C[3 * j + 2];
        int col = clamp5(x) * NC + clamp5(y);
        int s = atomicAdd(cntC + col, 1);
        if (s < COLCAP)
            Ccol[col * COLCAP + s] =
                make_float4(x, y, z, -LCONST * (x * x + y * y + z * z));
    }

    // ---- grid spin barrier (bar pre-zeroed by memset node) ----
    __syncthreads();                          // drains this block's stores
    if (threadIdx.x == 0) {
        __threadfence();                      // release: binned data device-visible
        atomicAdd(bar, 1u);
        while (atomicAdd(bar, 0u) < (unsigned)GRID1) {}
        __threadfence();                      // acquire: invalidate stale caches
    }
    __syncthreads();

    // ---- theta_C per dom slot (375 wave-tasks over 528 waves) ----
    int wv = t >> 6, lane = t & 63;
    if (wv < NTASKC) {
        int cell = wv / 3, chunk = wv % 3;
        int len = min(cntD[cell], DOMCAP) - chunk * 64;
        if (len > 0) {                        // wave-uniform
            int slot = cell * DOMCAP + chunk * 64 + lane;
            float4 d = make_float4(0.f, 0.f, 0.f, 0.f);   // sanitize poison lanes
            if (lane < len) d = PDbin[slot];
            float acc = scan_cols(d, cell / 25, (cell / 5) % 5, Ccol, cntC);
            TC[slot] = acc;                   // finite for all written slots
        }
    }
}

// Wave task = (b, cell, chunk-of-64-dom-points); one contiguous-run scan of
// the 9 neighbor columns of batch b, times precomputed TC, block-free reduce,
// ticket-finalize (round-4 proven) so no extra dispatch for the output.
__global__ void __launch_bounds__(256) k_main(const float4* __restrict__ PDbin,
                                              const float4* __restrict__ C1col,
                                              const float* __restrict__ TC,
                                              int* __restrict__ cnts,
                                              float* __restrict__ out) {
    const int* cntD  = cnts + W_CNTD;
    const int* cntC1 = cnts + W_CNTC1;
    float* prod = (float*)(cnts + W_PROD);
    unsigned* done = (unsigned*)(cnts + W_DONE);

    int lane = threadIdx.x & 63;
    int wtask = __builtin_amdgcn_readfirstlane(blockIdx.x * 4 + (threadIdx.x >> 6));
    int chunk = wtask % 3;
    int rest  = wtask / 3;
    int cell  = rest % NCELL;
    int b     = rest / NCELL;

    int len = __builtin_amdgcn_readfirstlane(min(cntD[cell], DOMCAP)) - chunk * 64;
    if (len > 0) {                            // wave-uniform
        int slot = cell * DOMCAP + chunk * 64 + lane;
        float4 d = make_float4(0.f, 0.f, 0.f, 0.f);   // sanitize poison lanes
        if (lane < len) d = PDbin[slot];
        float acc = scan_cols(d, cell / 25, (cell / 5) % 5,
                              C1col + (size_t)b * (NCOL * COLCAP), cntC1 + b * NCOL);
        float v = (lane < len) ? acc * TC[slot] : 0.0f;  // select: NaN-safe
        for (int off = 32; off; off >>= 1) v += __shfl_down(v, off, 64);
        if (lane == 0) atomicAdd(prod + b, v);
    }

    // ticket finalize: every wave (live or empty) arrives; 6000th writes out.
    __threadfence();
    unsigned old = 0;
    if (lane == 0) old = atomicAdd(done, 1u);
    old = __shfl(old, 0, 64);
    if (old == NTASK - 1) {
        __threadfence();
        if (lane < 16) {
            const float scale = 4.76837158203125e-4f;  // A*V/1024
            float p = atomicAdd(prod + lane, 0.0f);    // coherent read
            float dot = fminf(fmaxf(p * scale, 0.0f), 1.0f);
            out[lane] = 1.0f - dot;
        }
    }
}

extern "C" void kernel_launch(void* const* d_in, const int* in_sizes, int n_in,
                              void* d_out, int out_size, void* d_ws, size_t ws_size,
                              hipStream_t stream) {
    const float* C1  = (const float*)d_in[0];   // (16,1024,3)
    const float* C   = (const float*)d_in[1];   // (1024,3)
    const float* dom = (const float*)d_in[2];   // (16384,3)
    float* out = (float*)d_out;                 // (16,)

    char* ws = (char*)d_ws;
    float4* PDbin = (float4*)(ws + 0);          // 125*192*16    =  384000
    float4* C1col = (float4*)(ws + 384000);     // 16*25*96*16   =  614400 ->  998400
    float4* Ccol  = (float4*)(ws + 998400);     // 25*96*16      =   38400 -> 1036800
    float*  TC    = (float*)(ws + 1036800);     // 125*192*4     =   96000 -> 1132800
    int*    cnts  = (int*)(ws + 1132800);       // 568 words     -> 1135072 (~1.1MB)

    hipMemsetAsync(cnts, 0, W_TOTAL * 4, stream);   // zeroes counters+ticket+barrier
    k_bin<<<GRID1, 256, 0, stream>>>(C1, C, dom, PDbin, C1col, Ccol, TC, cnts);
    k_main<<<MAIN_BLOCKS, 256, 0, stream>>>(PDbin, C1col, TC, cnts, out);
}